// Round 19
// baseline (107.531 us; speedup 1.0000x reference)
//
#include <hip/hip_runtime.h>
#include <math.h>

typedef __attribute__((ext_vector_type(8))) short short8v;
typedef __attribute__((ext_vector_type(4))) float f32x4;

static constexpr float RCf = 5.0f;
static constexpr float PIf = 3.14159265358979323846f;
static constexpr int NPAD = 4096;
static constexpr int BINCAP = 128;   // max pairs/atom; Binom(160k,1/4000) 14-sigma

__device__ inline unsigned short f2bf(float f) {
    union { float f; unsigned u; } x; x.f = f;
    unsigned u = x.u;
    unsigned r = (u + 0x7fffu + ((u >> 16) & 1u)) >> 16;
    return (unsigned short)r;
}

__device__ inline void wave_lds_fence() {
    asm volatile("s_waitcnt lgkmcnt(0)" ::: "memory");
    __builtin_amdgcn_wave_barrier();
}

// ---------------------------------------------------------------------------
// Fused pre-kernel:
//   [0,625)    : pair binning — pdata[i*128+slot] = (x_j,y_j,z_j,species_j)
//   [625,1153) : W1sym prep (MFMA B-frag layout)
//   [1153,1217): W2 transpose (frag layout); block 1216 also zeroes out[40]
// ---------------------------------------------------------------------------
__global__ __launch_bounds__(256) void pre_kernel(
    const int* __restrict__ pairs, const float* __restrict__ pos,
    const int* __restrict__ species, int* __restrict__ cursor,
    float4* __restrict__ pdata, int n_pairs,
    const float* __restrict__ W1, const float* __restrict__ gamma,
    const float* __restrict__ beta, unsigned short* __restrict__ W1symF,
    float* __restrict__ b1,
    const float* __restrict__ W2, unsigned short* __restrict__ W2F,
    float* __restrict__ out)
{
    __shared__ float tile[64][65];
    int bid = blockIdx.x;
    int t = threadIdx.x;

    if (bid < 625) {
        int p = bid * 256 + t;
        if (p < n_pairs) {
            int i = pairs[2 * p], j = pairs[2 * p + 1];
            float4 v;
            v.x = pos[3 * j]; v.y = pos[3 * j + 1]; v.z = pos[3 * j + 2];
            union { int i; float f; } c; c.i = species[j];
            v.w = c.f;
            int slot = atomicAdd(&cursor[i], 1);
            pdata[(size_t)i * BINCAP + slot] = v;
        }
        return;
    }
    if (bid < 1153) {
        int id = bid - 625;
        int q = id / 132;
        int u0 = (id % 132) * 16;
        int h = t;
        int l = u0 / 528, r = u0 % 528;
        int A = 0;
        while ((A + 1) * 32 - (A + 1) * A / 2 <= r) A++;
        int B = A + (r - (A * 32 - A * (A - 1) / 2));

        const float* W1q = W1 + (size_t)q * 4096 * 256;
        float bacc = 0.0f;
        short8v buf0, buf1;
#pragma unroll
        for (int uu = 0; uu < 16; uu++) {
            int pos1 = l * 1024 + (A >> 3) * 256 + (B >> 3) * 64 + (A & 7) * 8 + (B & 7);
            float w1 = W1q[(size_t)pos1 * 256 + h];
            float v = gamma[pos1] * w1;
            bacc += beta[pos1] * w1;
            if (A < B) {
                int pos2 = l * 1024 + (B >> 3) * 256 + (A >> 3) * 64 + (B & 7) * 8 + (A & 7);
                float w2 = W1q[(size_t)pos2 * 256 + h];
                v += gamma[pos2] * w2;
                bacc += beta[pos2] * w2;
            }
            unsigned short bv = f2bf(v);
            if (uu < 8) buf0[uu] = (short)bv; else buf1[uu - 8] = (short)bv;
            B++;
            if (B == 32) { A++; B = A; if (A == 32) { A = 0; B = 0; l++; } }
        }
        int hg = q * 256 + h;
        size_t base = ((size_t)(hg >> 4) * 66 + (u0 >> 5)) * 512
                    + ((((u0 >> 3) & 3) << 4) | (hg & 15)) * 8;
        *(short8v*)(W1symF + base) = buf0;
        *(short8v*)(W1symF + base + 128) = buf1;
        atomicAdd(&b1[q * 256 + h], bacc);
        return;
    }
    int id2 = bid - 1153;            // [0,64)
    if (id2 == 63 && t < 40) out[t] = 0.0f;
    int k0 = (id2 & 3) * 64, n0 = ((id2 >> 2) & 3) * 64, q = id2 >> 4;
    const float* Wq = W2 + (size_t)q * 256 * 256;
    int kl = t >> 6, nl = t & 63;
#pragma unroll
    for (int i = 0; i < 16; i++)
        tile[kl + i * 4][nl] = Wq[(size_t)(k0 + kl + i * 4) * 256 + n0 + nl];
    __syncthreads();
#pragma unroll
    for (int rr = 0; rr < 2; rr++) {
        int s = t + rr * 256;
        int ft = s >> 6, l = s & 63;
        int n_loc = (ft & 3) * 16 + (l & 15);
        int k_loc = (ft >> 2) * 32 + (l >> 4) * 8;
        short8v v;
#pragma unroll
        for (int j = 0; j < 8; j++) v[j] = (short)f2bf(tile[k_loc + j][n_loc]);
        int nt = (n0 >> 4) + (ft & 3);
        int kt = (k0 >> 5) + (ft >> 2);
        *(short8v*)(W2F + (size_t)q * 65536 + ((size_t)nt * 8 + kt) * 512 + l * 8) = v;
    }
}

// ---------------------------------------------------------------------------
// Fused gather + power-spectrum + LayerNorm -> unique-position bf16 Fu.
// grid = n_atoms (4000): Fu pad rows keep stale data; harmless — MFMA mixes
// only K, so garbage affects only pad OUTPUT rows, guarded downstream.
// ---------------------------------------------------------------------------
__global__ __launch_bounds__(256) void gather_atom_kernel(
    const float* __restrict__ pos, const float4* __restrict__ pdata,
    const int* __restrict__ cursor, const float* __restrict__ W_rad,
    const float* __restrict__ W_alch, unsigned short* __restrict__ Fu,
    int n_atoms)
{
    int atom = blockIdx.x;
    int t = threadIdx.x;
    __shared__ float wr2[512];
    __shared__ float raw_sh[4][16][16];
    __shared__ float Y_sh[4][16][16];
    __shared__ float wal_sh[4][16][4];
    __shared__ float R_sh[4][16][32];
    __shared__ float part[4][512];
    __shared__ float c_sh[512];
    __shared__ float red[8];

    for (int u = t; u < 512; u += 256) {
        int l = u >> 7, rr = (u >> 3) & 15, n = u & 7;
        wr2[rr * 32 + l * 8 + n] = W_rad[u];
    }

    int npair = cursor[atom];
    float px = pos[3 * atom], py = pos[3 * atom + 1], pz = pos[3 * atom + 2];
    const float4* pd_base = pdata + (size_t)atom * BINCAP;

    int ss = t >> 6, lane = t & 63;
    int a_pos = lane >> 4, lm_pos = lane & 15;
    int lof_pos = (lm_pos > 0) + (lm_pos > 3) + (lm_pos > 8);
    float accn[8] = {0.f, 0.f, 0.f, 0.f, 0.f, 0.f, 0.f, 0.f};

    __syncthreads();

    int nl_r = lane & 31;
    int pg = lane >> 5;
    float wvreg[16];
#pragma unroll
    for (int rr = 0; rr < 16; rr++) wvreg[rr] = wr2[rr * 32 + nl_r];

    int p_loc = lane >> 2, qq = lane & 3;

    for (int pb = ss * 16; pb < npair; pb += 64) {
        int nc = npair - pb; if (nc > 16) nc = 16;
        if (p_loc < nc) {
            float4 pd = pd_base[pb + p_loc];
            union { float f; int i; } c; c.f = pd.w;
            int sj = c.i;
            float dx = pd.x - px;
            float dy = pd.y - py;
            float dz = pd.z - pz;
            float r = sqrtf(dx * dx + dy * dy + dz * dz + 1e-12f);
            float inv = 1.0f / r;
            float xx = dx * inv, yy = dy * inv, zz = dz * inv;
            float fc = (r < RCf) ? 0.5f * (cosf((PIf / RCf) * r) + 1.0f) : 0.0f;
            float x2 = xx * xx, y2 = yy * yy, z2 = zz * zz;
#pragma unroll
            for (int w = 0; w < 4; w++) {
                int rr = qq * 4 + w;
                float mu = (RCf / 15.0f) * (float)rr;
                float tt = (r - mu) * (16.0f / RCf);
                raw_sh[ss][p_loc][rr] = expf(-tt * tt) * fc;
                int lmv = qq * 4 + w;
                float yv;
                switch (lmv) {
                    case 0:  yv = 0.28209479177387814f; break;
                    case 1:  yv = 0.4886025119029199f * yy; break;
                    case 2:  yv = 0.4886025119029199f * zz; break;
                    case 3:  yv = 0.4886025119029199f * xx; break;
                    case 4:  yv = 1.0925484305920792f * xx * yy; break;
                    case 5:  yv = 1.0925484305920792f * yy * zz; break;
                    case 6:  yv = 0.31539156525252005f * (3.0f * z2 - 1.0f); break;
                    case 7:  yv = 1.0925484305920792f * xx * zz; break;
                    case 8:  yv = 0.5462742152960396f * (x2 - y2); break;
                    case 9:  yv = 0.5900435899266435f * yy * (3.0f * x2 - y2); break;
                    case 10: yv = 2.890611442640554f * xx * yy * zz; break;
                    case 11: yv = 0.4570457994644658f * yy * (5.0f * z2 - 1.0f); break;
                    case 12: yv = 0.3731763325901154f * zz * (5.0f * z2 - 3.0f); break;
                    case 13: yv = 0.4570457994644658f * xx * (5.0f * z2 - 1.0f); break;
                    case 14: yv = 1.445305721320277f * zz * (x2 - y2); break;
                    default: yv = 0.5900435899266435f * xx * (x2 - 3.0f * y2); break;
                }
                Y_sh[ss][p_loc][lmv] = yv;
            }
            wal_sh[ss][p_loc][qq] = W_alch[sj * 4 + qq];
        }
        wave_lds_fence();
#pragma unroll
        for (int r8 = 0; r8 < 8; r8++) {
            int p = pg * 8 + r8;
            if (p < nc) {
                const float4* rw4 = (const float4*)raw_sh[ss][p];
                float4 a0 = rw4[0], a1 = rw4[1], a2 = rw4[2], a3 = rw4[3];
                float acc = 0.f;
                acc = fmaf(a0.x, wvreg[0], acc);
                acc = fmaf(a0.y, wvreg[1], acc);
                acc = fmaf(a0.z, wvreg[2], acc);
                acc = fmaf(a0.w, wvreg[3], acc);
                acc = fmaf(a1.x, wvreg[4], acc);
                acc = fmaf(a1.y, wvreg[5], acc);
                acc = fmaf(a1.z, wvreg[6], acc);
                acc = fmaf(a1.w, wvreg[7], acc);
                acc = fmaf(a2.x, wvreg[8], acc);
                acc = fmaf(a2.y, wvreg[9], acc);
                acc = fmaf(a2.z, wvreg[10], acc);
                acc = fmaf(a2.w, wvreg[11], acc);
                acc = fmaf(a3.x, wvreg[12], acc);
                acc = fmaf(a3.y, wvreg[13], acc);
                acc = fmaf(a3.z, wvreg[14], acc);
                acc = fmaf(a3.w, wvreg[15], acc);
                R_sh[ss][p][nl_r] = acc;
            }
        }
        wave_lds_fence();
        for (int p = 0; p < nc; p++) {
            float wy = wal_sh[ss][p][a_pos] * Y_sh[ss][p][lm_pos];
            const float4* rp = (const float4*)&R_sh[ss][p][lof_pos * 8];
            float4 r0 = rp[0], r1 = rp[1];
            accn[0] = fmaf(wy, r0.x, accn[0]);
            accn[1] = fmaf(wy, r0.y, accn[1]);
            accn[2] = fmaf(wy, r0.z, accn[2]);
            accn[3] = fmaf(wy, r0.w, accn[3]);
            accn[4] = fmaf(wy, r1.x, accn[4]);
            accn[5] = fmaf(wy, r1.y, accn[5]);
            accn[6] = fmaf(wy, r1.z, accn[6]);
            accn[7] = fmaf(wy, r1.w, accn[7]);
        }
        wave_lds_fence();
    }

#pragma unroll
    for (int n = 0; n < 8; n++)
        part[ss][a_pos * 128 + lm_pos * 8 + n] = accn[n];
    __syncthreads();
    c_sh[t]       = part[0][t]       + part[1][t]       + part[2][t]       + part[3][t];
    c_sh[t + 256] = part[0][t + 256] + part[1][t + 256] + part[2][t + 256] + part[3][t + 256];
    __syncthreads();

    const float invsq[4] = {1.0f, 0.57735026918962576f, 0.44721359549995794f,
                            0.37796447300922722f};
    int b = t >> 6, n = (t >> 3) & 7, k = t & 7;
    float fv[16];
    float lsum = 0.0f;
#pragma unroll
    for (int l = 0; l < 4; l++) {
        int base = l * l;
        int cntm = 2 * l + 1;
        float f0 = 0.f, f1 = 0.f, f2 = 0.f, f3 = 0.f;
        for (int m = 0; m < cntm; m++) {
            int ro = (base + m) * 8;
            float cb = c_sh[b * 128 + ro + k];
            f0 = fmaf(c_sh[0 * 128 + ro + n], cb, f0);
            f1 = fmaf(c_sh[1 * 128 + ro + n], cb, f1);
            f2 = fmaf(c_sh[2 * 128 + ro + n], cb, f2);
            f3 = fmaf(c_sh[3 * 128 + ro + n], cb, f3);
        }
        fv[l * 4 + 0] = f0 * invsq[l];
        fv[l * 4 + 1] = f1 * invsq[l];
        fv[l * 4 + 2] = f2 * invsq[l];
        fv[l * 4 + 3] = f3 * invsq[l];
    }
#pragma unroll
    for (int ii = 0; ii < 16; ii++) lsum += fv[ii];

    float v = lsum;
#pragma unroll
    for (int o = 1; o < 64; o <<= 1) v += __shfl_xor(v, o, 64);
    int wid = t >> 6, lane2 = t & 63;
    if (lane2 == 0) red[wid] = v;
    __syncthreads();
    float mean = (red[0] + red[1] + red[2] + red[3]) * (1.0f / 4096.0f);

    float lss = 0.0f;
#pragma unroll
    for (int ii = 0; ii < 16; ii++) {
        float d = fv[ii] - mean;
        lss += d * d;
    }
    v = lss;
#pragma unroll
    for (int o = 1; o < 64; o <<= 1) v += __shfl_xor(v, o, 64);
    if (lane2 == 0) red[4 + wid] = v;
    __syncthreads();
    float var = (red[4] + red[5] + red[6] + red[7]) * (1.0f / 4096.0f);
    float rs = rsqrtf(var + 1e-5f);

    unsigned short* Fo = Fu + (size_t)atom * 2112;
    int B = b * 8 + k;
#pragma unroll
    for (int ii = 0; ii < 16; ii++) {
        int l = ii >> 2, a = ii & 3;
        int A = a * 8 + n;
        if (A <= B) {
            int u = l * 528 + A * 32 - (A * (A + 1)) / 2 + B;
            Fo[u] = f2bf((fv[ii] - mean) * rs);
        }
    }
}

// ---------------------------------------------------------------------------
// bf16 MFMA GEMM — 128x64 tile, grid 512; A via global_load_lds (16 KB single
// buffer); B frag-linear from global, register double-buffered.
//   MODE 1: K=2112; v=(acc+b1[gcol])*alch; silu -> bf16 H1 (all rows).
//   MODE 2: per-q K=256; fused W_last dot + SEGMENT-SUM: block LDS acc40
//           reduce -> atomicAdd out (final_seg kernel + e32 buffer removed;
//           slot (q=0,by=0,wc=0) adds comp_w once per atom).
// ---------------------------------------------------------------------------
template<int MODE>
__global__ __launch_bounds__(256) void gemm_mfma(
    const unsigned short* __restrict__ A, const unsigned short* __restrict__ BF,
    void* __restrict__ C, int M, int K, long sAq, long sBq,
    const int* __restrict__ species, const float* __restrict__ W_alch,
    const float* __restrict__ W_last, const float* __restrict__ b1,
    const float* __restrict__ comp_w, const int* __restrict__ sid)
{
    __shared__ unsigned short As[128 * 64];
    __shared__ float acc40[40];
    int t = threadIdx.x, w = t >> 6, lane = t & 63;
    int bm = blockIdx.x * 128, bn = blockIdx.y * 64;
    int q = blockIdx.z;

    if (MODE == 2) {
        if (t < 40) acc40[t] = 0.0f;
    }

    const unsigned short* Aq = A + (size_t)q * sAq;
    const unsigned short* BFq = BF + (size_t)q * sBq;
    int ldab = K * 2;
    int KT = K >> 5;

    long srcoff = (long)(lane >> 3) * ldab + (long)(((lane & 7) ^ (lane >> 3)) << 4);
    const char* Ab = (const char*)Aq + (size_t)bm * ldab + srcoff;

    int wr = w >> 1, wc = w & 1;
    f32x4 acc[4][2];
#pragma unroll
    for (int i = 0; i < 4; i++)
#pragma unroll
        for (int j = 0; j < 2; j++) acc[i][j] = (f32x4){0.f, 0.f, 0.f, 0.f};

    int l15 = lane & 15, l16 = lane >> 4;
    int rA0 = wr * 64 + l15;
    int cb0 = l16 * 16;
    int swzA = (rA0 & 7) << 4;
    int nt0 = (bn >> 4) + wc * 2;
    const unsigned short* bbase = BFq + lane * 8;

    auto stageA = [&](int k0) {
        long kb = (long)k0 * 2;
#pragma unroll
        for (int i = 0; i < 4; i++) {
            int c = w * 4 + i;
            __builtin_amdgcn_global_load_lds(
                (const __attribute__((address_space(1))) unsigned int*)(Ab + (size_t)(c * 8) * ldab + kb),
                (__attribute__((address_space(3))) unsigned int*)(As + c * 512), 16, 0, 0);
        }
    };
    auto loadB = [&](short8v (&bf)[2][2], int k0) {
#pragma unroll
        for (int nb = 0; nb < 2; nb++)
#pragma unroll
            for (int kk = 0; kk < 2; kk++)
                bf[nb][kk] = *(const short8v*)(bbase
                    + ((size_t)(nt0 + nb) * KT + (k0 >> 5) + kk) * 512);
    };
    auto compute = [&](const short8v (&bf)[2][2]) {
        short8v a[4][2];
#pragma unroll
        for (int mb = 0; mb < 4; mb++)
#pragma unroll
            for (int kk = 0; kk < 2; kk++) {
                int addr = (rA0 + mb * 16) * 128 + ((cb0 + kk * 64) ^ swzA);
                a[mb][kk] = *(const short8v*)((const char*)As + addr);
            }
#pragma unroll
        for (int kk = 0; kk < 2; kk++)
#pragma unroll
            for (int mb = 0; mb < 4; mb++)
#pragma unroll
                for (int nb = 0; nb < 2; nb++)
                    acc[mb][nb] = __builtin_amdgcn_mfma_f32_16x16x32_bf16(
                        a[mb][kk], bf[nb][kk], acc[mb][nb], 0, 0, 0);
    };

    short8v bA[2][2], bB[2][2];
    loadB(bA, 0);
    int k0 = 0;
    while (true) {
        stageA(k0);
        __syncthreads();
        if (k0 + 64 < K) loadB(bB, k0 + 64);
        compute(bA);
        __syncthreads();
        k0 += 64;
        if (k0 >= K) break;
        stageA(k0);
        __syncthreads();
        if (k0 + 64 < K) loadB(bA, k0 + 64);
        compute(bB);
        __syncthreads();
        k0 += 64;
        if (k0 >= K) break;
    }

    int colbase = bn + wc * 32 + l15;
    if (MODE == 1) {
#pragma unroll
        for (int mb = 0; mb < 4; mb++) {
#pragma unroll
            for (int j = 0; j < 4; j++) {
                int row = bm + wr * 64 + mb * 16 + l16 * 4 + j;
                int sp = species[row < M ? row : (M - 1)];
#pragma unroll
                for (int nb = 0; nb < 2; nb++) {
                    int gcol = colbase + nb * 16;
                    int qq = gcol >> 8, hc = gcol & 255;
                    float v = (acc[mb][nb][j] + b1[gcol]) * W_alch[sp * 4 + qq];
                    v = v / (1.0f + expf(-v));
                    ((unsigned short*)C)[((size_t)qq * 4096 + row) * 256 + hc] = f2bf(v);
                }
            }
        }
    } else {
        float wl0 = W_last[q * 256 + colbase];
        float wl1 = W_last[q * 256 + colbase + 16];
        bool lead = (q == 0 && blockIdx.y == 0 && wc == 0);
#pragma unroll
        for (int mb = 0; mb < 4; mb++) {
#pragma unroll
            for (int j = 0; j < 4; j++) {
                int row = bm + wr * 64 + mb * 16 + l16 * 4 + j;
                float v0 = acc[mb][0][j]; v0 = v0 / (1.0f + expf(-v0));
                float v1 = acc[mb][1][j]; v1 = v1 / (1.0f + expf(-v1));
                float part = v0 * wl0 + v1 * wl1;
                part += __shfl_xor(part, 1, 64);
                part += __shfl_xor(part, 2, 64);
                part += __shfl_xor(part, 4, 64);
                part += __shfl_xor(part, 8, 64);
                if (l15 == 0 && row < M) {
                    if (lead) part += comp_w[species[row]];
                    atomicAdd(&acc40[sid[row]], part);
                }
            }
        }
        __syncthreads();
        if (t < 40) {
            float v = acc40[t];
            if (v != 0.0f) atomicAdd(&((float*)C)[t], v * 0.5f);
        }
    }
}

// ---------------------------------------------------------------------------
extern "C" void kernel_launch(void* const* d_in, const int* in_sizes, int n_in,
                              void* d_out, int out_size, void* d_ws, size_t ws_size,
                              hipStream_t stream)
{
    const float* pos     = (const float*)d_in[0];
    const int*   pairs   = (const int*)d_in[1];
    const int*   species = (const int*)d_in[2];
    const int*   sid     = (const int*)d_in[3];
    const float* W_rad   = (const float*)d_in[4];
    const float* W_alch  = (const float*)d_in[5];
    const float* gamma   = (const float*)d_in[6];
    const float* beta    = (const float*)d_in[7];
    const float* W1      = (const float*)d_in[8];
    const float* W2      = (const float*)d_in[9];
    const float* W_last  = (const float*)d_in[10];
    const float* comp_w  = (const float*)d_in[11];

    int n_atoms = in_sizes[0] / 3;   // 4000
    int n_pairs = in_sizes[1] / 2;   // 160000
    float* out = (float*)d_out;

    char* ws = (char*)d_ws;
    int*   cursor = (int*)(ws);                                   // 16 KB
    float* b1     = (float*)(ws + 16384);                         // 4 KB
    size_t o0 = 20480;
    float4* pdata = (float4*)(ws + o0);                           // 8 MB
    size_t o1 = o0 + (size_t)NPAD * BINCAP * 16;
    unsigned short* W1symF = (unsigned short*)(ws + o1);          // frag 64nt x 66kt x 512
    size_t o2 = o1 + (size_t)1024 * 2112 * 2;
    unsigned short* W2F = (unsigned short*)(ws + o2);             // frag 4 x 16nt x 8kt x 512
    size_t o3 = o2 + (size_t)4 * 256 * 256 * 2;
    unsigned short* Fu = (unsigned short*)(ws + o3);              // 4096 x 2112 bf16
    size_t o4 = o3 + (size_t)4096 * 2112 * 2;
    unsigned short* H1 = (unsigned short*)(ws + o4);              // 4 x 4096 x 256 bf16

    hipMemsetAsync(ws, 0, 20480, stream);          // cursor + b1

    // fused: pair binning (625) | W1sym prep (528) | W2 frag + out zero (64)
    pre_kernel<<<1217, 256, 0, stream>>>(
        pairs, pos, species, cursor, pdata, n_pairs,
        W1, gamma, beta, W1symF, b1, W2, W2F, out);

    gather_atom_kernel<<<n_atoms, 256, 0, stream>>>(
        pos, pdata, cursor, W_rad, W_alch, Fu, n_atoms);

    // GEMM1: Fu [4096 x 2112] @ W1symF (frag) -> H1 (bf16)
    gemm_mfma<1><<<dim3(32, 16, 1), 256, 0, stream>>>(
        Fu, W1symF, H1, n_atoms, 2112, 0L, 0L, species, W_alch, W_last, b1,
        comp_w, sid);

    // GEMM2: H1[q] [4096 x 256] @ W2F[q] (frag) -> fused segment-sum -> out
    gemm_mfma<2><<<dim3(32, 4, 4), 256, 0, stream>>>(
        H1, W2F, out, n_atoms, 256, 4096L * 256, 65536L, species, W_alch, W_last, b1,
        comp_w, sid);
}

// Round 20
// 102.819 us; speedup vs baseline: 1.0458x; 1.0458x over previous
//
#include <hip/hip_runtime.h>
#include <math.h>

typedef __attribute__((ext_vector_type(8))) short short8v;
typedef __attribute__((ext_vector_type(4))) float f32x4;

static constexpr float RCf = 5.0f;
static constexpr float PIf = 3.14159265358979323846f;
static constexpr int NPAD = 4096;
static constexpr int BINCAP = 128;   // max pairs/atom; Binom(160k,1/4000) 14-sigma

__device__ inline unsigned short f2bf(float f) {
    union { float f; unsigned u; } x; x.f = f;
    unsigned u = x.u;
    unsigned r = (u + 0x7fffu + ((u >> 16) & 1u)) >> 16;
    return (unsigned short)r;
}

__device__ inline void wave_lds_fence() {
    asm volatile("s_waitcnt lgkmcnt(0)" ::: "memory");
    __builtin_amdgcn_wave_barrier();
}

// ---------------------------------------------------------------------------
// Fused pre-kernel:
//   [0,625)    : pair binning — pdata[i*128+slot] = (x_j,y_j,z_j,species_j)
//   [625,1153) : W1sym prep (MFMA B-frag layout)
//   [1153,1217): W2 transpose (frag layout); block 1216 also zeroes out[40]
// ---------------------------------------------------------------------------
__global__ __launch_bounds__(256) void pre_kernel(
    const int* __restrict__ pairs, const float* __restrict__ pos,
    const int* __restrict__ species, int* __restrict__ cursor,
    float4* __restrict__ pdata, int n_pairs,
    const float* __restrict__ W1, const float* __restrict__ gamma,
    const float* __restrict__ beta, unsigned short* __restrict__ W1symF,
    float* __restrict__ b1,
    const float* __restrict__ W2, unsigned short* __restrict__ W2F,
    float* __restrict__ out)
{
    __shared__ float tile[64][65];
    int bid = blockIdx.x;
    int t = threadIdx.x;

    if (bid < 625) {
        int p = bid * 256 + t;
        if (p < n_pairs) {
            int i = pairs[2 * p], j = pairs[2 * p + 1];
            float4 v;
            v.x = pos[3 * j]; v.y = pos[3 * j + 1]; v.z = pos[3 * j + 2];
            union { int i; float f; } c; c.i = species[j];
            v.w = c.f;
            int slot = atomicAdd(&cursor[i], 1);
            pdata[(size_t)i * BINCAP + slot] = v;
        }
        return;
    }
    if (bid < 1153) {
        int id = bid - 625;
        int q = id / 132;
        int u0 = (id % 132) * 16;
        int h = t;
        int l = u0 / 528, r = u0 % 528;
        int A = 0;
        while ((A + 1) * 32 - (A + 1) * A / 2 <= r) A++;
        int B = A + (r - (A * 32 - A * (A - 1) / 2));

        const float* W1q = W1 + (size_t)q * 4096 * 256;
        float bacc = 0.0f;
        short8v buf0, buf1;
#pragma unroll
        for (int uu = 0; uu < 16; uu++) {
            int pos1 = l * 1024 + (A >> 3) * 256 + (B >> 3) * 64 + (A & 7) * 8 + (B & 7);
            float w1 = W1q[(size_t)pos1 * 256 + h];
            float v = gamma[pos1] * w1;
            bacc += beta[pos1] * w1;
            if (A < B) {
                int pos2 = l * 1024 + (B >> 3) * 256 + (A >> 3) * 64 + (B & 7) * 8 + (A & 7);
                float w2 = W1q[(size_t)pos2 * 256 + h];
                v += gamma[pos2] * w2;
                bacc += beta[pos2] * w2;
            }
            unsigned short bv = f2bf(v);
            if (uu < 8) buf0[uu] = (short)bv; else buf1[uu - 8] = (short)bv;
            B++;
            if (B == 32) { A++; B = A; if (A == 32) { A = 0; B = 0; l++; } }
        }
        int hg = q * 256 + h;
        size_t base = ((size_t)(hg >> 4) * 66 + (u0 >> 5)) * 512
                    + ((((u0 >> 3) & 3) << 4) | (hg & 15)) * 8;
        *(short8v*)(W1symF + base) = buf0;
        *(short8v*)(W1symF + base + 128) = buf1;
        atomicAdd(&b1[q * 256 + h], bacc);
        return;
    }
    int id2 = bid - 1153;            // [0,64)
    if (id2 == 63 && t < 40) out[t] = 0.0f;
    int k0 = (id2 & 3) * 64, n0 = ((id2 >> 2) & 3) * 64, q = id2 >> 4;
    const float* Wq = W2 + (size_t)q * 256 * 256;
    int kl = t >> 6, nl = t & 63;
#pragma unroll
    for (int i = 0; i < 16; i++)
        tile[kl + i * 4][nl] = Wq[(size_t)(k0 + kl + i * 4) * 256 + n0 + nl];
    __syncthreads();
#pragma unroll
    for (int rr = 0; rr < 2; rr++) {
        int s = t + rr * 256;
        int ft = s >> 6, l = s & 63;
        int n_loc = (ft & 3) * 16 + (l & 15);
        int k_loc = (ft >> 2) * 32 + (l >> 4) * 8;
        short8v v;
#pragma unroll
        for (int j = 0; j < 8; j++) v[j] = (short)f2bf(tile[k_loc + j][n_loc]);
        int nt = (n0 >> 4) + (ft & 3);
        int kt = (k0 >> 5) + (ft >> 2);
        *(short8v*)(W2F + (size_t)q * 65536 + ((size_t)nt * 8 + kt) * 512 + l * 8) = v;
    }
}

// ---------------------------------------------------------------------------
// Fused gather + power-spectrum + LayerNorm -> unique-position bf16 Fu.
// (r18 structure: pdata payload loads, wave-independent chunks, grid NPAD)
// ---------------------------------------------------------------------------
__global__ __launch_bounds__(256) void gather_atom_kernel(
    const float* __restrict__ pos, const float4* __restrict__ pdata,
    const int* __restrict__ cursor, const float* __restrict__ W_rad,
    const float* __restrict__ W_alch, unsigned short* __restrict__ Fu,
    int n_atoms)
{
    int atom = blockIdx.x;
    int t = threadIdx.x;
    __shared__ float wr2[512];
    __shared__ float raw_sh[4][16][16];
    __shared__ float Y_sh[4][16][16];
    __shared__ float wal_sh[4][16][4];
    __shared__ float R_sh[4][16][32];
    __shared__ float part[4][512];
    __shared__ float c_sh[512];
    __shared__ float red[8];

    for (int u = t; u < 512; u += 256) {
        int l = u >> 7, rr = (u >> 3) & 15, n = u & 7;
        wr2[rr * 32 + l * 8 + n] = W_rad[u];
    }

    int npair = cursor[atom];

    float px = 0.f, py = 0.f, pz = 0.f;
    if (atom < n_atoms) {
        px = pos[3 * atom]; py = pos[3 * atom + 1]; pz = pos[3 * atom + 2];
    }
    const float4* pd_base = pdata + (size_t)atom * BINCAP;

    int ss = t >> 6, lane = t & 63;
    int a_pos = lane >> 4, lm_pos = lane & 15;
    int lof_pos = (lm_pos > 0) + (lm_pos > 3) + (lm_pos > 8);
    float accn[8] = {0.f, 0.f, 0.f, 0.f, 0.f, 0.f, 0.f, 0.f};

    __syncthreads();

    int nl_r = lane & 31;
    int pg = lane >> 5;
    float wvreg[16];
#pragma unroll
    for (int rr = 0; rr < 16; rr++) wvreg[rr] = wr2[rr * 32 + nl_r];

    int p_loc = lane >> 2, qq = lane & 3;

    for (int pb = ss * 16; pb < npair; pb += 64) {
        int nc = npair - pb; if (nc > 16) nc = 16;
        if (p_loc < nc) {
            float4 pd = pd_base[pb + p_loc];
            union { float f; int i; } c; c.f = pd.w;
            int sj = c.i;
            float dx = pd.x - px;
            float dy = pd.y - py;
            float dz = pd.z - pz;
            float r = sqrtf(dx * dx + dy * dy + dz * dz + 1e-12f);
            float inv = 1.0f / r;
            float xx = dx * inv, yy = dy * inv, zz = dz * inv;
            float fc = (r < RCf) ? 0.5f * (cosf((PIf / RCf) * r) + 1.0f) : 0.0f;
            float x2 = xx * xx, y2 = yy * yy, z2 = zz * zz;
#pragma unroll
            for (int w = 0; w < 4; w++) {
                int rr = qq * 4 + w;
                float mu = (RCf / 15.0f) * (float)rr;
                float tt = (r - mu) * (16.0f / RCf);
                raw_sh[ss][p_loc][rr] = expf(-tt * tt) * fc;
                int lmv = qq * 4 + w;
                float yv;
                switch (lmv) {
                    case 0:  yv = 0.28209479177387814f; break;
                    case 1:  yv = 0.4886025119029199f * yy; break;
                    case 2:  yv = 0.4886025119029199f * zz; break;
                    case 3:  yv = 0.4886025119029199f * xx; break;
                    case 4:  yv = 1.0925484305920792f * xx * yy; break;
                    case 5:  yv = 1.0925484305920792f * yy * zz; break;
                    case 6:  yv = 0.31539156525252005f * (3.0f * z2 - 1.0f); break;
                    case 7:  yv = 1.0925484305920792f * xx * zz; break;
                    case 8:  yv = 0.5462742152960396f * (x2 - y2); break;
                    case 9:  yv = 0.5900435899266435f * yy * (3.0f * x2 - y2); break;
                    case 10: yv = 2.890611442640554f * xx * yy * zz; break;
                    case 11: yv = 0.4570457994644658f * yy * (5.0f * z2 - 1.0f); break;
                    case 12: yv = 0.3731763325901154f * zz * (5.0f * z2 - 3.0f); break;
                    case 13: yv = 0.4570457994644658f * xx * (5.0f * z2 - 1.0f); break;
                    case 14: yv = 1.445305721320277f * zz * (x2 - y2); break;
                    default: yv = 0.5900435899266435f * xx * (x2 - 3.0f * y2); break;
                }
                Y_sh[ss][p_loc][lmv] = yv;
            }
            wal_sh[ss][p_loc][qq] = W_alch[sj * 4 + qq];
        }
        wave_lds_fence();
#pragma unroll
        for (int r8 = 0; r8 < 8; r8++) {
            int p = pg * 8 + r8;
            if (p < nc) {
                const float4* rw4 = (const float4*)raw_sh[ss][p];
                float4 a0 = rw4[0], a1 = rw4[1], a2 = rw4[2], a3 = rw4[3];
                float acc = 0.f;
                acc = fmaf(a0.x, wvreg[0], acc);
                acc = fmaf(a0.y, wvreg[1], acc);
                acc = fmaf(a0.z, wvreg[2], acc);
                acc = fmaf(a0.w, wvreg[3], acc);
                acc = fmaf(a1.x, wvreg[4], acc);
                acc = fmaf(a1.y, wvreg[5], acc);
                acc = fmaf(a1.z, wvreg[6], acc);
                acc = fmaf(a1.w, wvreg[7], acc);
                acc = fmaf(a2.x, wvreg[8], acc);
                acc = fmaf(a2.y, wvreg[9], acc);
                acc = fmaf(a2.z, wvreg[10], acc);
                acc = fmaf(a2.w, wvreg[11], acc);
                acc = fmaf(a3.x, wvreg[12], acc);
                acc = fmaf(a3.y, wvreg[13], acc);
                acc = fmaf(a3.z, wvreg[14], acc);
                acc = fmaf(a3.w, wvreg[15], acc);
                R_sh[ss][p][nl_r] = acc;
            }
        }
        wave_lds_fence();
        for (int p = 0; p < nc; p++) {
            float wy = wal_sh[ss][p][a_pos] * Y_sh[ss][p][lm_pos];
            const float4* rp = (const float4*)&R_sh[ss][p][lof_pos * 8];
            float4 r0 = rp[0], r1 = rp[1];
            accn[0] = fmaf(wy, r0.x, accn[0]);
            accn[1] = fmaf(wy, r0.y, accn[1]);
            accn[2] = fmaf(wy, r0.z, accn[2]);
            accn[3] = fmaf(wy, r0.w, accn[3]);
            accn[4] = fmaf(wy, r1.x, accn[4]);
            accn[5] = fmaf(wy, r1.y, accn[5]);
            accn[6] = fmaf(wy, r1.z, accn[6]);
            accn[7] = fmaf(wy, r1.w, accn[7]);
        }
        wave_lds_fence();
    }

#pragma unroll
    for (int n = 0; n < 8; n++)
        part[ss][a_pos * 128 + lm_pos * 8 + n] = accn[n];
    __syncthreads();
    c_sh[t]       = part[0][t]       + part[1][t]       + part[2][t]       + part[3][t];
    c_sh[t + 256] = part[0][t + 256] + part[1][t + 256] + part[2][t + 256] + part[3][t + 256];
    __syncthreads();

    const float invsq[4] = {1.0f, 0.57735026918962576f, 0.44721359549995794f,
                            0.37796447300922722f};
    int b = t >> 6, n = (t >> 3) & 7, k = t & 7;
    float fv[16];
    float lsum = 0.0f;
#pragma unroll
    for (int l = 0; l < 4; l++) {
        int base = l * l;
        int cntm = 2 * l + 1;
        float f0 = 0.f, f1 = 0.f, f2 = 0.f, f3 = 0.f;
        for (int m = 0; m < cntm; m++) {
            int ro = (base + m) * 8;
            float cb = c_sh[b * 128 + ro + k];
            f0 = fmaf(c_sh[0 * 128 + ro + n], cb, f0);
            f1 = fmaf(c_sh[1 * 128 + ro + n], cb, f1);
            f2 = fmaf(c_sh[2 * 128 + ro + n], cb, f2);
            f3 = fmaf(c_sh[3 * 128 + ro + n], cb, f3);
        }
        fv[l * 4 + 0] = f0 * invsq[l];
        fv[l * 4 + 1] = f1 * invsq[l];
        fv[l * 4 + 2] = f2 * invsq[l];
        fv[l * 4 + 3] = f3 * invsq[l];
    }
#pragma unroll
    for (int ii = 0; ii < 16; ii++) lsum += fv[ii];

    float v = lsum;
#pragma unroll
    for (int o = 1; o < 64; o <<= 1) v += __shfl_xor(v, o, 64);
    int wid = t >> 6, lane2 = t & 63;
    if (lane2 == 0) red[wid] = v;
    __syncthreads();
    float mean = (red[0] + red[1] + red[2] + red[3]) * (1.0f / 4096.0f);

    float lss = 0.0f;
#pragma unroll
    for (int ii = 0; ii < 16; ii++) {
        float d = fv[ii] - mean;
        lss += d * d;
    }
    v = lss;
#pragma unroll
    for (int o = 1; o < 64; o <<= 1) v += __shfl_xor(v, o, 64);
    if (lane2 == 0) red[4 + wid] = v;
    __syncthreads();
    float var = (red[4] + red[5] + red[6] + red[7]) * (1.0f / 4096.0f);
    float rs = rsqrtf(var + 1e-5f);

    unsigned short* Fo = Fu + (size_t)atom * 2112;
    int B = b * 8 + k;
#pragma unroll
    for (int ii = 0; ii < 16; ii++) {
        int l = ii >> 2, a = ii & 3;
        int A = a * 8 + n;
        if (A <= B) {
            int u = l * 528 + A * 32 - (A * (A + 1)) / 2 + B;
            Fo[u] = f2bf((fv[ii] - mean) * rs);
        }
    }
}

// ---------------------------------------------------------------------------
// bf16 MFMA GEMM — 128x64 tile, grid 512 (2 blocks/CU); B frag-linear from
// global in register dbuf; As now PING-PONG double-buffered (32 KB — cheap
// since B left LDS in r12; r5's dbuf failure was at 48 KB with B in LDS).
// One barrier per K-step; staging overlaps the full compute phase (T3).
//   MODE 1: K=2112; v=(acc+b1[gcol])*alch; silu -> bf16 H1 (all rows).
//   MODE 2: per-q K=256; fused W_last dot -> e32[q*8+by*2+wc][row].
// ---------------------------------------------------------------------------
template<int MODE>
__global__ __launch_bounds__(256) void gemm_mfma(
    const unsigned short* __restrict__ A, const unsigned short* __restrict__ BF,
    void* __restrict__ C, int M, int K, long sAq, long sBq,
    const int* __restrict__ species, const float* __restrict__ W_alch,
    const float* __restrict__ W_last, const float* __restrict__ b1)
{
    __shared__ unsigned short As[2][128 * 64];  // 32 KB
    int t = threadIdx.x, w = t >> 6, lane = t & 63;
    int bm = blockIdx.x * 128, bn = blockIdx.y * 64;
    int q = blockIdx.z;

    const unsigned short* Aq = A + (size_t)q * sAq;
    const unsigned short* BFq = BF + (size_t)q * sBq;
    int ldab = K * 2;
    int KT = K >> 5;

    long srcoff = (long)(lane >> 3) * ldab + (long)(((lane & 7) ^ (lane >> 3)) << 4);
    const char* Ab = (const char*)Aq + (size_t)bm * ldab + srcoff;

    int wr = w >> 1, wc = w & 1;
    f32x4 acc[4][2];
#pragma unroll
    for (int i = 0; i < 4; i++)
#pragma unroll
        for (int j = 0; j < 2; j++) acc[i][j] = (f32x4){0.f, 0.f, 0.f, 0.f};

    int l15 = lane & 15, l16 = lane >> 4;
    int rA0 = wr * 64 + l15;
    int cb0 = l16 * 16;
    int swzA = (rA0 & 7) << 4;
    int nt0 = (bn >> 4) + wc * 2;
    const unsigned short* bbase = BFq + lane * 8;

    auto stageA = [&](int buf, int k0) {
        long kb = (long)k0 * 2;
#pragma unroll
        for (int i = 0; i < 4; i++) {
            int c = w * 4 + i;
            __builtin_amdgcn_global_load_lds(
                (const __attribute__((address_space(1))) unsigned int*)(Ab + (size_t)(c * 8) * ldab + kb),
                (__attribute__((address_space(3))) unsigned int*)(&As[buf][c * 512]), 16, 0, 0);
        }
    };
    auto loadB = [&](short8v (&bf)[2][2], int k0) {
#pragma unroll
        for (int nb = 0; nb < 2; nb++)
#pragma unroll
            for (int kk = 0; kk < 2; kk++)
                bf[nb][kk] = *(const short8v*)(bbase
                    + ((size_t)(nt0 + nb) * KT + (k0 >> 5) + kk) * 512);
    };
    auto compute = [&](int buf, const short8v (&bf)[2][2]) {
        short8v a[4][2];
#pragma unroll
        for (int mb = 0; mb < 4; mb++)
#pragma unroll
            for (int kk = 0; kk < 2; kk++) {
                int addr = (rA0 + mb * 16) * 128 + ((cb0 + kk * 64) ^ swzA);
                a[mb][kk] = *(const short8v*)((const char*)&As[buf][0] + addr);
            }
#pragma unroll
        for (int kk = 0; kk < 2; kk++)
#pragma unroll
            for (int mb = 0; mb < 4; mb++)
#pragma unroll
                for (int nb = 0; nb < 2; nb++)
                    acc[mb][nb] = __builtin_amdgcn_mfma_f32_16x16x32_bf16(
                        a[mb][kk], bf[nb][kk], acc[mb][nb], 0, 0, 0);
    };

    short8v bA[2][2], bB[2][2];
    stageA(0, 0);
    loadB(bA, 0);
    __syncthreads();
    int k0 = 0;
    while (true) {
        int cur = (k0 >> 6) & 1;
        if (k0 + 64 < K) { stageA(cur ^ 1, k0 + 64); loadB(bB, k0 + 64); }
        compute(cur, bA);
        k0 += 64;
        if (k0 >= K) break;
        __syncthreads();
        cur = (k0 >> 6) & 1;
        if (k0 + 64 < K) { stageA(cur ^ 1, k0 + 64); loadB(bA, k0 + 64); }
        compute(cur, bB);
        k0 += 64;
        if (k0 >= K) break;
        __syncthreads();
    }

    int colbase = bn + wc * 32 + l15;
    if (MODE == 1) {
#pragma unroll
        for (int mb = 0; mb < 4; mb++) {
#pragma unroll
            for (int j = 0; j < 4; j++) {
                int row = bm + wr * 64 + mb * 16 + l16 * 4 + j;
                int sp = species[row < M ? row : (M - 1)];
#pragma unroll
                for (int nb = 0; nb < 2; nb++) {
                    int gcol = colbase + nb * 16;
                    int qq = gcol >> 8, hc = gcol & 255;
                    float v = (acc[mb][nb][j] + b1[gcol]) * W_alch[sp * 4 + qq];
                    v = v / (1.0f + expf(-v));
                    ((unsigned short*)C)[((size_t)qq * 4096 + row) * 256 + hc] = f2bf(v);
                }
            }
        }
    } else {
        float wl0 = W_last[q * 256 + colbase];
        float wl1 = W_last[q * 256 + colbase + 16];
        float* e32 = (float*)C;
        int slot = q * 8 + blockIdx.y * 2 + wc;
#pragma unroll
        for (int mb = 0; mb < 4; mb++) {
#pragma unroll
            for (int j = 0; j < 4; j++) {
                int row = bm + wr * 64 + mb * 16 + l16 * 4 + j;
                float v0 = acc[mb][0][j]; v0 = v0 / (1.0f + expf(-v0));
                float v1 = acc[mb][1][j]; v1 = v1 / (1.0f + expf(-v1));
                float part = v0 * wl0 + v1 * wl1;
                part += __shfl_xor(part, 1, 64);
                part += __shfl_xor(part, 2, 64);
                part += __shfl_xor(part, 4, 64);
                part += __shfl_xor(part, 8, 64);
                if (l15 == 0) e32[(size_t)slot * 4096 + row] = part;
            }
        }
    }
}

// ---------------------------------------------------------------------------
// Final segment-sum (16 blocks): out[sid[a]] += 0.5*(sum_k e32[k][a]+comp_w)
// (out zeroed by pre_kernel block 1216)
// ---------------------------------------------------------------------------
__global__ __launch_bounds__(256) void final_seg(
    const float* __restrict__ e32, const float* __restrict__ comp_w,
    const int* __restrict__ species, const int* __restrict__ sid,
    float* __restrict__ out, int n_atoms)
{
    __shared__ float acc40[40];
    int t = threadIdx.x;
    if (t < 40) acc40[t] = 0.0f;
    __syncthreads();
    int a = blockIdx.x * 256 + t;
    if (a < n_atoms) {
        float s = comp_w[species[a]];
#pragma unroll
        for (int k = 0; k < 32; k++) s += e32[(size_t)k * 4096 + a];
        atomicAdd(&acc40[sid[a]], s * 0.5f);
    }
    __syncthreads();
    if (t < 40 && acc40[t] != 0.0f) atomicAdd(&out[t], acc40[t]);
}

// ---------------------------------------------------------------------------
extern "C" void kernel_launch(void* const* d_in, const int* in_sizes, int n_in,
                              void* d_out, int out_size, void* d_ws, size_t ws_size,
                              hipStream_t stream)
{
    const float* pos     = (const float*)d_in[0];
    const int*   pairs   = (const int*)d_in[1];
    const int*   species = (const int*)d_in[2];
    const int*   sid     = (const int*)d_in[3];
    const float* W_rad   = (const float*)d_in[4];
    const float* W_alch  = (const float*)d_in[5];
    const float* gamma   = (const float*)d_in[6];
    const float* beta    = (const float*)d_in[7];
    const float* W1      = (const float*)d_in[8];
    const float* W2      = (const float*)d_in[9];
    const float* W_last  = (const float*)d_in[10];
    const float* comp_w  = (const float*)d_in[11];

    int n_atoms = in_sizes[0] / 3;   // 4000
    int n_pairs = in_sizes[1] / 2;   // 160000
    float* out = (float*)d_out;

    char* ws = (char*)d_ws;
    int*   cursor = (int*)(ws);                                   // 16 KB
    float* b1     = (float*)(ws + 16384);                         // 4 KB
    size_t o0 = 20480;
    float4* pdata = (float4*)(ws + o0);                           // 8 MB
    size_t o1 = o0 + (size_t)NPAD * BINCAP * 16;
    unsigned short* W1symF = (unsigned short*)(ws + o1);          // frag 64nt x 66kt x 512
    size_t o2 = o1 + (size_t)1024 * 2112 * 2;
    unsigned short* W2F = (unsigned short*)(ws + o2);             // frag 4 x 16nt x 8kt x 512
    size_t o3 = o2 + (size_t)4 * 256 * 256 * 2;
    unsigned short* Fu = (unsigned short*)(ws + o3);              // 4096 x 2112 bf16
    size_t o4 = o3 + (size_t)4096 * 2112 * 2;
    unsigned short* H1 = (unsigned short*)(ws + o4);              // 4 x 4096 x 256 bf16
    size_t o5 = o4 + (size_t)4 * 4096 * 256 * 2;
    float* e32 = (float*)(ws + o5);                               // 32 x 4096 f32

    hipMemsetAsync(ws, 0, 20480, stream);          // cursor + b1

    // fused: pair binning (625) | W1sym prep (528) | W2 frag + out zero (64)
    pre_kernel<<<1217, 256, 0, stream>>>(
        pairs, pos, species, cursor, pdata, n_pairs,
        W1, gamma, beta, W1symF, b1, W2, W2F, out);

    gather_atom_kernel<<<NPAD, 256, 0, stream>>>(
        pos, pdata, cursor, W_rad, W_alch, Fu, n_atoms);

    // GEMM1: Fu [4096 x 2112] @ W1symF (frag) -> H1 (bf16)
    gemm_mfma<1><<<dim3(32, 16, 1), 256, 0, stream>>>(
        Fu, W1symF, H1, n_atoms, 2112, 0L, 0L, species, W_alch, W_last, b1);

    // GEMM2: H1[q] [4096 x 256] @ W2F[q] (frag) -> e32 partials
    gemm_mfma<2><<<dim3(32, 4, 4), 256, 0, stream>>>(
        H1, W2F, e32, n_atoms, 256, 4096L * 256, 65536L, species, W_alch, W_last, b1);

    final_seg<<<16, 256, 0, stream>>>(e32, comp_w, species, sid, out, n_atoms);
}